// Round 9
// baseline (2478.890 us; speedup 1.0000x reference)
//
#include <hip/hip_runtime.h>
#include <stdint.h>

#define NB   32
#define NC   256
#define NPTS 4096
#define KCL  8
#define KC   384          // OpenBLAS sgemm KC panel
#define PCH  256          // points per staged chunk in k_psum2
#define NCH  (NPTS/PCH)   // 16
#define PAD  260          // chunk row stride (16B-aligned, bank-spread)

// Contiguous-axis pairwise, numpy npyv SIMD path on AVX512 (nlanes=16):
// used for ||cent||^2. KEEP BIT-IDENTICAL to r6 (incl. the l+2+2 quirk).
__device__ float np_sumsq_avx512(const float* sh) {
  float half[2];
  #pragma unroll
  for (int h = 0; h < 2; ++h) {
    const float* ap = sh + h * 128;
    float rv[16];
    #pragma unroll
    for (int l = 0; l < 16; ++l) {
      float q[8];
      #pragma unroll
      for (int j = 0; j < 8; ++j) {
        float e = ap[16 * j + l];
        q[j] = __fmul_rn(e, e);
      }
      rv[l] = __fadd_rn(__fadd_rn(__fadd_rn(q[0], q[1]), __fadd_rn(q[2], q[3])),
                        __fadd_rn(__fadd_rn(q[4], q[5]), __fadd_rn(q[6], q[7])));
    }
    float t1[8];
    #pragma unroll
    for (int l = 0; l < 8; ++l) t1[l] = __fadd_rn(rv[l], rv[l + 8]);
    float t2[4];
    #pragma unroll
    for (int l = 0; l < 4; ++l) t2[l] = __fadd_rn(t1[l], t1[l + 2 + 2]);
    float t3[2];
    #pragma unroll
    for (int l = 0; l < 2; ++l) t3[l] = __fadd_rn(t2[l], t2[l + 2]);
    half[h] = __fadd_rn(t3[0], t3[1]);
  }
  return __fadd_rn(half[0], half[1]);
}

// ---------------- init: centroids = first 8 points ----------------
__global__ __launch_bounds__(256) void k_init(const float* __restrict__ X,
                                              float* __restrict__ centT,
                                              float* __restrict__ cnorm) {
  const int b = blockIdx.x >> 3, k = blockIdx.x & 7, c = threadIdx.x;
  __shared__ float sarr[NC];
  float v = X[(size_t)b * NC * NPTS + (size_t)c * NPTS + k];
  centT[(b * NC + c) * KCL + k] = v;
  sarr[c] = v;
  __syncthreads();
  if (c == 0) cnorm[b * KCL + k] = np_sumsq_avx512(sarr);
}

// -------- assign: no LDS, direct coalesced reads, 256 pts/block --------
// Bit-identical per-point arithmetic to r6: sequential-fold a, FMA-chain b,
// d = (a - 2b) + c, first-min argmin.
__global__ __launch_bounds__(256) void k_assign(const float* __restrict__ X,
                                                const float* __restrict__ centT,
                                                const float* __restrict__ cnorm,
                                                int* __restrict__ lab) {
  const int blk = blockIdx.x;            // 512 = 32 b * 16 tiles
  const int b   = blk >> 4;
  const int n0  = (blk & 15) << 8;
  const int t   = threadIdx.x;

  const float* Xp = X + (size_t)b * NC * NPTS + n0 + t;
  const float4* cw = (const float4*)(centT + (size_t)b * NC * KCL); // uniform

  float cnf[KCL];
  #pragma unroll
  for (int k = 0; k < KCL; ++k) cnf[k] = cnorm[b * KCL + k];

  float a = 0.f;
  float bb[KCL];
  #pragma unroll
  for (int k = 0; k < KCL; ++k) bb[k] = 0.f;

  #pragma unroll 8
  for (int c = 0; c < NC; ++c) {
    float x = Xp[(size_t)c * NPTS];      // lanes consecutive -> coalesced
    a = __fadd_rn(a, __fmul_rn(x, x));
    float4 c0 = cw[c * 2], c1 = cw[c * 2 + 1];
    bb[0] = __builtin_fmaf(x, c0.x, bb[0]);
    bb[1] = __builtin_fmaf(x, c0.y, bb[1]);
    bb[2] = __builtin_fmaf(x, c0.z, bb[2]);
    bb[3] = __builtin_fmaf(x, c0.w, bb[3]);
    bb[4] = __builtin_fmaf(x, c1.x, bb[4]);
    bb[5] = __builtin_fmaf(x, c1.y, bb[5]);
    bb[6] = __builtin_fmaf(x, c1.z, bb[6]);
    bb[7] = __builtin_fmaf(x, c1.w, bb[7]);
  }

  int lb = 0; float best = 3.4e38f;
  #pragma unroll
  for (int k = 0; k < KCL; ++k) {
    float d = __fadd_rn(__fsub_rn(a, __fmul_rn(2.0f, bb[k])), cnf[k]);
    if (d < best) { best = d; lb = k; }
  }
  lab[b * NPTS + n0 + t] = lb;
}

// -------- update: stream all points, panel-break chains (bit = r6) --------
// grid 256: b = blk>>3, cg = blk&7 (32 channels each). threads: k=t&7, cl=t>>3.
// !is_final: pa chains within KC=384 panels, C folds panels in order (== r6
//            k_psum+k_combine bits); writes centT.
// is_final:  continuous 4096-chain (== r6 k_final order); writes out.
__global__ __launch_bounds__(256) void k_psum2(const float* __restrict__ X,
                                               const int* __restrict__ lab,
                                               float* __restrict__ centT,
                                               float* __restrict__ out,
                                               int is_final) {
  const int blk = blockIdx.x, b = blk >> 3, cg = blk & 7;
  const int t = threadIdx.x, k = t & 7, cl = t >> 3;

  __shared__ __align__(16) int   labs[NPTS];          // 16 KB
  __shared__ __align__(16) float buf[2][32 * PAD];    // 65 KB

  for (int i = t; i < NPTS / 4; i += 256)
    ((int4*)labs)[i] = ((const int4*)(lab + b * NPTS))[i];

  const float* Xg = X + (size_t)b * NC * NPTS + (size_t)(cg * 32) * NPTS;

  float4 rg[8];
  // LOADC: chunk ch -> regs. wave w handles row r = i2*4+w, cols q*4..q*4+3.
  #define LOADC(ch)                                                        \
    _Pragma("unroll")                                                      \
    for (int i2 = 0; i2 < 8; ++i2) {                                       \
      int i = i2 * 256 + t;                                                \
      int r = i >> 6, q = i & 63;                                          \
      rg[i2] = *(const float4*)(Xg + (size_t)r * NPTS + (ch) * PCH + q * 4); \
    }
  #define WRITEC(bi)                                                       \
    _Pragma("unroll")                                                      \
    for (int i2 = 0; i2 < 8; ++i2) {                                       \
      int i = i2 * 256 + t;                                                \
      int r = i >> 6, q = i & 63;                                          \
      *(float4*)&buf[bi][r * PAD + q * 4] = rg[i2];                        \
    }

  LOADC(0); WRITEC(0);
  __syncthreads();

  float C = 0.f, pa = 0.f;
  int cnt = 0, nextbrk = KC;
  for (int ch = 0; ch < NCH; ++ch) {
    if (ch + 1 < NCH) LOADC(ch + 1);
    const float* bp = &buf[ch & 1][cl * PAD];
    const int pbase = ch * PCH;
    for (int j = 0; j < PCH / 4; ++j) {
      int p = pbase + j * 4;
      if (!is_final && p == nextbrk) {      // panel boundary (384 % 4 == 0)
        C = __fadd_rn(C, pa); pa = 0.f; nextbrk += KC;
      }
      int4   l4 = *(const int4*)&labs[p];
      float4 x4 = *(const float4*)&bp[j * 4];
      if (l4.x == k) { pa = __fadd_rn(pa, x4.x); ++cnt; }
      if (l4.y == k) { pa = __fadd_rn(pa, x4.y); ++cnt; }
      if (l4.z == k) { pa = __fadd_rn(pa, x4.z); ++cnt; }
      if (l4.w == k) { pa = __fadd_rn(pa, x4.w); ++cnt; }
    }
    if (ch + 1 < NCH) WRITEC((ch + 1) & 1);
    __syncthreads();
  }
  C = __fadd_rn(C, pa);   // last (partial) panel / exact 0+pa when is_final

  const int c = cg * 32 + cl;
  if (is_final) {
    out[(b * KCL + k) * NC + c] =
        (cnt > 0) ? __fdiv_rn(C, (float)cnt) : 0.0f;
  } else {
    const float mean = __fdiv_rn(C, (float)((cnt > 0) ? cnt : 1));
    const int ci = (b * NC + c) * KCL + k;
    float old = centT[ci];
    centT[ci] = (cnt > 0) ? mean : old;
  }
  #undef LOADC
  #undef WRITEC
}

// ---------------- cnorm from fresh centroids (bit = r6 tail) ----------------
__global__ __launch_bounds__(256) void k_norm(const float* __restrict__ centT,
                                              float* __restrict__ cnorm) {
  const int b = blockIdx.x >> 3, k = blockIdx.x & 7, c = threadIdx.x;
  __shared__ float sarr[NC];
  sarr[c] = centT[(b * NC + c) * KCL + k];
  __syncthreads();
  if (c == 0) cnorm[b * KCL + k] = np_sumsq_avx512(sarr);
}

extern "C" void kernel_launch(void* const* d_in, const int* in_sizes, int n_in,
                              void* d_out, int out_size, void* d_ws, size_t ws_size,
                              hipStream_t stream) {
  const float* X = (const float*)d_in[0];
  float* out = (float*)d_out;

  // ws: centT f[32*256*8] | cnorm f[32*8] | lab i[32*4096]   (~0.8 MB)
  float* centT = (float*)d_ws;
  float* cnorm = centT + (size_t)NB * NC * KCL;
  int*   lab   = (int*)(cnorm + NB * KCL);

  k_init<<<NB * KCL, 256, 0, stream>>>(X, centT, cnorm);
  for (int it = 0; it < 10; ++it) {
    k_assign<<<NB * 16, 256, 0, stream>>>(X, centT, cnorm, lab);
    k_psum2<<<NB * KCL, 256, 0, stream>>>(X, lab, centT, out, 0);
    k_norm<<<NB * KCL, 256, 0, stream>>>(centT, cnorm);
  }
  k_assign<<<NB * 16, 256, 0, stream>>>(X, centT, cnorm, lab);
  k_psum2<<<NB * KCL, 256, 0, stream>>>(X, lab, centT, out, 1);
}

// Round 10
// 2004.244 us; speedup vs baseline: 1.2368x; 1.2368x over previous
//
#include <hip/hip_runtime.h>
#include <stdint.h>

#define NB   32
#define NC   256
#define NPTS 4096
#define KCL  8
#define KC   384          // OpenBLAS sgemm KC panel
#define NPANEL 11         // 10*384 + 256

// Contiguous-axis pairwise, numpy npyv SIMD path on AVX512 (nlanes=16):
// used for ||cent||^2. KEEP BIT-IDENTICAL to r6 (incl. the l+2+2 quirk).
__device__ float np_sumsq_avx512(const float* sh) {
  float half[2];
  #pragma unroll
  for (int h = 0; h < 2; ++h) {
    const float* ap = sh + h * 128;
    float rv[16];
    #pragma unroll
    for (int l = 0; l < 16; ++l) {
      float q[8];
      #pragma unroll
      for (int j = 0; j < 8; ++j) {
        float e = ap[16 * j + l];
        q[j] = __fmul_rn(e, e);
      }
      rv[l] = __fadd_rn(__fadd_rn(__fadd_rn(q[0], q[1]), __fadd_rn(q[2], q[3])),
                        __fadd_rn(__fadd_rn(q[4], q[5]), __fadd_rn(q[6], q[7])));
    }
    float t1[8];
    #pragma unroll
    for (int l = 0; l < 8; ++l) t1[l] = __fadd_rn(rv[l], rv[l + 8]);
    float t2[4];
    #pragma unroll
    for (int l = 0; l < 4; ++l) t2[l] = __fadd_rn(t1[l], t1[l + 2 + 2]);
    float t3[2];
    #pragma unroll
    for (int l = 0; l < 2; ++l) t3[l] = __fadd_rn(t2[l], t2[l + 2]);
    half[h] = __fadd_rn(t3[0], t3[1]);
  }
  return __fadd_rn(half[0], half[1]);
}

// ---------------- init: centroids = first 8 points ----------------
__global__ __launch_bounds__(256) void k_init(const float* __restrict__ X,
                                              float* __restrict__ centT,
                                              float* __restrict__ cnorm) {
  const int b = blockIdx.x >> 3, k = blockIdx.x & 7, c = threadIdx.x;
  __shared__ float sarr[NC];
  float v = X[(size_t)b * NC * NPTS + (size_t)c * NPTS + k];
  centT[(b * NC + c) * KCL + k] = v;
  sarr[c] = v;
  __syncthreads();
  if (c == 0) cnorm[b * KCL + k] = np_sumsq_avx512(sarr);
}

// -------- assign: no LDS, direct coalesced reads (r9-proven bits) --------
__global__ __launch_bounds__(256) void k_assign(const float* __restrict__ X,
                                                const float* __restrict__ centT,
                                                const float* __restrict__ cnorm,
                                                int* __restrict__ lab) {
  const int blk = blockIdx.x;            // 512 = 32 b * 16 tiles
  const int b   = blk >> 4;
  const int n0  = (blk & 15) << 8;
  const int t   = threadIdx.x;

  const float* Xp = X + (size_t)b * NC * NPTS + n0 + t;
  const float4* cw = (const float4*)(centT + (size_t)b * NC * KCL); // uniform

  float cnf[KCL];
  #pragma unroll
  for (int k = 0; k < KCL; ++k) cnf[k] = cnorm[b * KCL + k];

  float a = 0.f;
  float bb[KCL];
  #pragma unroll
  for (int k = 0; k < KCL; ++k) bb[k] = 0.f;

  #pragma unroll 8
  for (int c = 0; c < NC; ++c) {
    float x = Xp[(size_t)c * NPTS];      // lanes consecutive -> coalesced
    a = __fadd_rn(a, __fmul_rn(x, x));
    float4 c0 = cw[c * 2], c1 = cw[c * 2 + 1];
    bb[0] = __builtin_fmaf(x, c0.x, bb[0]);
    bb[1] = __builtin_fmaf(x, c0.y, bb[1]);
    bb[2] = __builtin_fmaf(x, c0.z, bb[2]);
    bb[3] = __builtin_fmaf(x, c0.w, bb[3]);
    bb[4] = __builtin_fmaf(x, c1.x, bb[4]);
    bb[5] = __builtin_fmaf(x, c1.y, bb[5]);
    bb[6] = __builtin_fmaf(x, c1.z, bb[6]);
    bb[7] = __builtin_fmaf(x, c1.w, bb[7]);
  }

  int lb = 0; float best = 3.4e38f;
  #pragma unroll
  for (int k = 0; k < KCL; ++k) {
    float d = __fadd_rn(__fsub_rn(a, __fmul_rn(2.0f, bb[k])), cnf[k]);
    if (d < best) { best = d; lb = k; }
  }
  lab[b * NPTS + n0 + t] = lb;
}

// ---- per-panel partial sums (r6 bit pattern), transposed conflict-free LDS ----
// block = (b, panel, cg): 2816 blocks. threads: k = t&7, cl = t>>3.
__global__ __launch_bounds__(256) void k_psum(const float* __restrict__ X,
                                              const int* __restrict__ lab,
                                              float* __restrict__ pp,
                                              int* __restrict__ pc) {
  const int blk = blockIdx.x;
  const int b = blk / 88, r = blk % 88, panel = r >> 3, cg = r & 7;
  const int p0 = panel * KC;
  const int len = (panel < 10) ? KC : (NPTS - 10 * KC);   // 384 or 256
  const int t = threadIdx.x, k = t & 7, cl = t >> 3;

  __shared__ __align__(16) float buf[KC][33];   // 50.7 KB, transposed [pt][ch]
  __shared__ __align__(16) int   labs[KC];

  for (int i = t; i < KC; i += 256)
    labs[i] = (i < len) ? lab[b * NPTS + p0 + i] : -1;
  const float* Xb = X + (size_t)b * NC * NPTS + (size_t)(cg * 32) * NPTS + p0;
  for (int i = t; i < 32 * KC; i += 256) {      // 48 scalar stores/thread
    int c = i / KC, p = i - c * KC;             // lanes: consecutive p, same c
    buf[p][c] = (p < len) ? Xb[(size_t)c * NPTS + p] : 0.f;  // bank (p+c)%32
  }
  __syncthreads();

  // chain: same arithmetic order as r6 k_psum (x,y,z,w per 4-group)
  float pa = 0.f; int cnt = 0;
  for (int j = 0; j < len; j += 4) {
    int4 l4 = *(const int4*)&labs[j];           // uniform -> broadcast
    if (l4.x == k) { pa = __fadd_rn(pa, buf[j + 0][cl]); ++cnt; }
    if (l4.y == k) { pa = __fadd_rn(pa, buf[j + 1][cl]); ++cnt; }
    if (l4.z == k) { pa = __fadd_rn(pa, buf[j + 2][cl]); ++cnt; }
    if (l4.w == k) { pa = __fadd_rn(pa, buf[j + 3][cl]); ++cnt; }
  }
  pp[(size_t)((b * NPANEL + panel) * KCL + k) * NC + cg * 32 + cl] = pa;
  if (cl == 0) pc[(b * NPANEL + panel) * KCL + k] = cnt;
}

// ---------------- ordered panel combine -> centroids + cnorm (r6 verbatim) ----
__global__ __launch_bounds__(256) void k_combine(const float* __restrict__ pp,
                                                 const int* __restrict__ pc,
                                                 float* __restrict__ centT,
                                                 float* __restrict__ cnorm) {
  const int b = blockIdx.x >> 3, k = blockIdx.x & 7, c = threadIdx.x;
  float C = 0.f;          // 0 + x exact: ordered fold == BLAS C-update
  int cnt = 0;
  for (int pnl = 0; pnl < NPANEL; ++pnl) {
    C = __fadd_rn(C, pp[(size_t)((b * NPANEL + pnl) * KCL + k) * NC + c]);
    cnt += pc[(b * NPANEL + pnl) * KCL + k];
  }
  const float mean = __fdiv_rn(C, (float)((cnt > 0) ? cnt : 1));
  const int ci = (b * NC + c) * KCL + k;
  float nv = (cnt > 0) ? mean : centT[ci];
  centT[ci] = nv;
  __shared__ float sarr[NC];
  sarr[c] = nv;
  __syncthreads();
  if (c == 0) cnorm[b * KCL + k] = np_sumsq_avx512(sarr);
}

// ---------------- final output: fold panels -> means ----------------
__global__ __launch_bounds__(256) void k_out(const float* __restrict__ pp,
                                             const int* __restrict__ pc,
                                             float* __restrict__ out) {
  const int b = blockIdx.x >> 3, k = blockIdx.x & 7, c = threadIdx.x;
  float C = 0.f;
  int cnt = 0;
  for (int pnl = 0; pnl < NPANEL; ++pnl) {
    C = __fadd_rn(C, pp[(size_t)((b * NPANEL + pnl) * KCL + k) * NC + c]);
    cnt += pc[(b * NPANEL + pnl) * KCL + k];
  }
  out[(b * KCL + k) * NC + c] =
      (cnt > 0) ? __fdiv_rn(C, (float)cnt) : 0.0f;
}

extern "C" void kernel_launch(void* const* d_in, const int* in_sizes, int n_in,
                              void* d_out, int out_size, void* d_ws, size_t ws_size,
                              hipStream_t stream) {
  const float* X = (const float*)d_in[0];
  float* out = (float*)d_out;

  // ws: centT f[32*256*8] | cnorm f[32*8] | lab i[32*4096] |
  //     pp f[32*11*8*256] | pc i[32*11*8]     (~3.7 MB)
  float* centT = (float*)d_ws;
  float* cnorm = centT + (size_t)NB * NC * KCL;
  int*   lab   = (int*)(cnorm + NB * KCL);
  float* pp    = (float*)(lab + (size_t)NB * NPTS);
  int*   pc    = (int*)(pp + (size_t)NB * NPANEL * KCL * NC);

  k_init<<<NB * KCL, 256, 0, stream>>>(X, centT, cnorm);
  for (int it = 0; it < 10; ++it) {
    k_assign<<<NB * 16, 256, 0, stream>>>(X, centT, cnorm, lab);
    k_psum<<<NB * NPANEL * KCL, 256, 0, stream>>>(X, lab, pp, pc);
    k_combine<<<NB * KCL, 256, 0, stream>>>(pp, pc, centT, cnorm);
  }
  k_assign<<<NB * 16, 256, 0, stream>>>(X, centT, cnorm, lab);
  k_psum<<<NB * NPANEL * KCL, 256, 0, stream>>>(X, lab, pp, pc);
  k_out<<<NB * KCL, 256, 0, stream>>>(pp, pc, out);
}

// Round 11
// 739.766 us; speedup vs baseline: 3.3509x; 2.7093x over previous
//
#include <hip/hip_runtime.h>
#include <stdint.h>

#define NB   32
#define NC   256
#define NPTS 4096
#define KCL  8
#define KC   384          // OpenBLAS sgemm KC panel
#define NPANEL 11         // 10*384 + 256
#define BSTRIDE 388       // buf row stride (floats): 16B-aligned, read-spread

// Contiguous-axis pairwise, numpy npyv SIMD path on AVX512 (nlanes=16):
// used for ||cent||^2. KEEP BIT-IDENTICAL to r6 (incl. the l+2+2 quirk).
__device__ float np_sumsq_avx512(const float* sh) {
  float half[2];
  #pragma unroll
  for (int h = 0; h < 2; ++h) {
    const float* ap = sh + h * 128;
    float rv[16];
    #pragma unroll
    for (int l = 0; l < 16; ++l) {
      float q[8];
      #pragma unroll
      for (int j = 0; j < 8; ++j) {
        float e = ap[16 * j + l];
        q[j] = __fmul_rn(e, e);
      }
      rv[l] = __fadd_rn(__fadd_rn(__fadd_rn(q[0], q[1]), __fadd_rn(q[2], q[3])),
                        __fadd_rn(__fadd_rn(q[4], q[5]), __fadd_rn(q[6], q[7])));
    }
    float t1[8];
    #pragma unroll
    for (int l = 0; l < 8; ++l) t1[l] = __fadd_rn(rv[l], rv[l + 8]);
    float t2[4];
    #pragma unroll
    for (int l = 0; l < 4; ++l) t2[l] = __fadd_rn(t1[l], t1[l + 2 + 2]);
    float t3[2];
    #pragma unroll
    for (int l = 0; l < 2; ++l) t3[l] = __fadd_rn(t2[l], t2[l + 2]);
    half[h] = __fadd_rn(t3[0], t3[1]);
  }
  return __fadd_rn(half[0], half[1]);
}

// ---------------- init: centroids = first 8 points ----------------
__global__ __launch_bounds__(256) void k_init(const float* __restrict__ X,
                                              float* __restrict__ centT,
                                              float* __restrict__ cnorm) {
  const int b = blockIdx.x >> 3, k = blockIdx.x & 7, c = threadIdx.x;
  __shared__ float sarr[NC];
  float v = X[(size_t)b * NC * NPTS + (size_t)c * NPTS + k];
  centT[(b * NC + c) * KCL + k] = v;
  sarr[c] = v;
  __syncthreads();
  if (c == 0) cnorm[b * KCL + k] = np_sumsq_avx512(sarr);
}

// -------- assign: no LDS, direct coalesced reads (r9/r10-proven bits) --------
__global__ __launch_bounds__(256) void k_assign(const float* __restrict__ X,
                                                const float* __restrict__ centT,
                                                const float* __restrict__ cnorm,
                                                int* __restrict__ lab) {
  const int blk = blockIdx.x;            // 512 = 32 b * 16 tiles
  const int b   = blk >> 4;
  const int n0  = (blk & 15) << 8;
  const int t   = threadIdx.x;

  const float* Xp = X + (size_t)b * NC * NPTS + n0 + t;
  const float4* cw = (const float4*)(centT + (size_t)b * NC * KCL); // uniform

  float cnf[KCL];
  #pragma unroll
  for (int k = 0; k < KCL; ++k) cnf[k] = cnorm[b * KCL + k];

  float a = 0.f;
  float bb[KCL];
  #pragma unroll
  for (int k = 0; k < KCL; ++k) bb[k] = 0.f;

  #pragma unroll 8
  for (int c = 0; c < NC; ++c) {
    float x = Xp[(size_t)c * NPTS];      // lanes consecutive -> coalesced
    a = __fadd_rn(a, __fmul_rn(x, x));
    float4 c0 = cw[c * 2], c1 = cw[c * 2 + 1];
    bb[0] = __builtin_fmaf(x, c0.x, bb[0]);
    bb[1] = __builtin_fmaf(x, c0.y, bb[1]);
    bb[2] = __builtin_fmaf(x, c0.z, bb[2]);
    bb[3] = __builtin_fmaf(x, c0.w, bb[3]);
    bb[4] = __builtin_fmaf(x, c1.x, bb[4]);
    bb[5] = __builtin_fmaf(x, c1.y, bb[5]);
    bb[6] = __builtin_fmaf(x, c1.z, bb[6]);
    bb[7] = __builtin_fmaf(x, c1.w, bb[7]);
  }

  int lb = 0; float best = 3.4e38f;
  #pragma unroll
  for (int k = 0; k < KCL; ++k) {
    float d = __fadd_rn(__fsub_rn(a, __fmul_rn(2.0f, bb[k])), cnf[k]);
    if (d < best) { best = d; lb = k; }
  }
  lab[b * NPTS + n0 + t] = lb;
}

// ---- per-panel partial sums: counting-sort + member-only ordered chains ----
// block = (b, panel, cg): 2816 blocks. threads: k = t&7, cl = t>>3.
// Fold sequence per (k,channel) is ascending point order within the panel —
// bit-identical to r10's conditional walk.
__global__ __launch_bounds__(256) void k_psum(const float* __restrict__ X,
                                              const int* __restrict__ lab,
                                              float* __restrict__ pp,
                                              int* __restrict__ pc) {
  const int blk = blockIdx.x;
  const int b = blk / 88, r = blk % 88, panel = r >> 3, cg = r & 7;
  const int p0 = panel * KC;
  const int len = (panel < 10) ? KC : (NPTS - 10 * KC);   // 384 or 256
  const int t = threadIdx.x, k = t & 7, cl = t >> 3, lane = t & 63;

  __shared__ __align__(16) float buf[32 * BSTRIDE];  // 49.7 KB, [ch][pt]
  __shared__ int perm[KC];
  __shared__ int wcnt[6][KCL];       // per-64-chunk, per-k counts
  __shared__ int cbase[6][KCL];      // chunk base offset within cluster list
  __shared__ int offs[KCL], hist[KCL];

  // ---- stage: float4 global -> float4 LDS, conflict-free ----
  const float* Xb = X + (size_t)b * NC * NPTS + (size_t)(cg * 32) * NPTS + p0;
  if (len == KC) {
    #pragma unroll
    for (int i2 = 0; i2 < 12; ++i2) {            // 32ch * 96 p4 / 256
      int i = i2 * 256 + t;
      int c = i / 96, q4 = i - c * 96;
      float4 v = *(const float4*)(Xb + (size_t)c * NPTS + q4 * 4);
      *(float4*)&buf[c * BSTRIDE + q4 * 4] = v;
    }
  } else {
    #pragma unroll
    for (int i2 = 0; i2 < 8; ++i2) {             // 32ch * 64 p4 / 256
      int i = i2 * 256 + t;
      int c = i >> 6, q4 = i & 63;
      float4 v = *(const float4*)(Xb + (size_t)c * NPTS + q4 * 4);
      *(float4*)&buf[c * BSTRIDE + q4 * 4] = v;
    }
  }

  // ---- ballot counting sort (stable, ascending point order) ----
  const int* Lb = lab + b * NPTS + p0;
  const uint64_t lt = (1ull << lane) - 1ull;
  int ml0, ml1, rk0 = 0, rk1 = 0;
  {
    const int q = t;                 // chunk = t>>6 in 0..3
    ml0 = (q < len) ? Lb[q] : -1;
    const int chunk = q >> 6;
    #pragma unroll
    for (int kk = 0; kk < KCL; ++kk) {
      uint64_t m = __ballot(ml0 == kk);
      if (lane == 0) wcnt[chunk][kk] = (int)__popcll(m);
      if (ml0 == kk) rk0 = (int)__popcll(m & lt);
    }
  }
  {
    const int q = 256 + t;           // chunk in 4..7 (6,7 invalid & guarded)
    ml1 = (q < len) ? Lb[q] : -1;
    const int chunk = q >> 6;
    #pragma unroll
    for (int kk = 0; kk < KCL; ++kk) {
      uint64_t m = __ballot(ml1 == kk);
      if (lane == 0 && chunk < 6) wcnt[chunk][kk] = (int)__popcll(m);
      if (ml1 == kk) rk1 = (int)__popcll(m & lt);
    }
  }
  __syncthreads();
  if (t == 0) {
    int rr = 0;
    for (int kk = 0; kk < KCL; ++kk) {
      int s = 0;
      #pragma unroll
      for (int ch = 0; ch < 6; ++ch) { cbase[ch][kk] = rr + s; s += wcnt[ch][kk]; }
      offs[kk] = rr; hist[kk] = s; rr += s;
    }
  }
  __syncthreads();
  if (ml0 >= 0) perm[cbase[t >> 6][ml0] + rk0] = t;
  if (ml1 >= 0) perm[cbase[(256 + t) >> 6][ml1] + rk1] = 256 + t;
  __syncthreads();

  // ---- member-only ordered chain: n_k dependent fadds (not 384) ----
  const int base = offs[k], n = hist[k];
  const float* bp = &buf[cl * BSTRIDE];
  float pa = 0.f;
  #pragma unroll 4
  for (int i = 0; i < n; ++i) {
    int p = perm[base + i];          // broadcast per k
    pa = __fadd_rn(pa, bp[p]);
  }
  pp[(size_t)((b * NPANEL + panel) * KCL + k) * NC + cg * 32 + cl] = pa;
  if (cl == 0) pc[(b * NPANEL + panel) * KCL + k] = n;
}

// ---------------- ordered panel combine -> centroids + cnorm (r6 verbatim) ----
__global__ __launch_bounds__(256) void k_combine(const float* __restrict__ pp,
                                                 const int* __restrict__ pc,
                                                 float* __restrict__ centT,
                                                 float* __restrict__ cnorm) {
  const int b = blockIdx.x >> 3, k = blockIdx.x & 7, c = threadIdx.x;
  float C = 0.f;          // 0 + x exact: ordered fold == BLAS C-update
  int cnt = 0;
  for (int pnl = 0; pnl < NPANEL; ++pnl) {
    C = __fadd_rn(C, pp[(size_t)((b * NPANEL + pnl) * KCL + k) * NC + c]);
    cnt += pc[(b * NPANEL + pnl) * KCL + k];
  }
  const float mean = __fdiv_rn(C, (float)((cnt > 0) ? cnt : 1));
  const int ci = (b * NC + c) * KCL + k;
  float nv = (cnt > 0) ? mean : centT[ci];
  centT[ci] = nv;
  __shared__ float sarr[NC];
  sarr[c] = nv;
  __syncthreads();
  if (c == 0) cnorm[b * KCL + k] = np_sumsq_avx512(sarr);
}

// ---------------- final output: fold panels -> means ----------------
__global__ __launch_bounds__(256) void k_out(const float* __restrict__ pp,
                                             const int* __restrict__ pc,
                                             float* __restrict__ out) {
  const int b = blockIdx.x >> 3, k = blockIdx.x & 7, c = threadIdx.x;
  float C = 0.f;
  int cnt = 0;
  for (int pnl = 0; pnl < NPANEL; ++pnl) {
    C = __fadd_rn(C, pp[(size_t)((b * NPANEL + pnl) * KCL + k) * NC + c]);
    cnt += pc[(b * NPANEL + pnl) * KCL + k];
  }
  out[(b * KCL + k) * NC + c] =
      (cnt > 0) ? __fdiv_rn(C, (float)cnt) : 0.0f;
}

extern "C" void kernel_launch(void* const* d_in, const int* in_sizes, int n_in,
                              void* d_out, int out_size, void* d_ws, size_t ws_size,
                              hipStream_t stream) {
  const float* X = (const float*)d_in[0];
  float* out = (float*)d_out;

  // ws: centT f[32*256*8] | cnorm f[32*8] | lab i[32*4096] |
  //     pp f[32*11*8*256] | pc i[32*11*8]     (~3.7 MB)
  float* centT = (float*)d_ws;
  float* cnorm = centT + (size_t)NB * NC * KCL;
  int*   lab   = (int*)(cnorm + NB * KCL);
  float* pp    = (float*)(lab + (size_t)NB * NPTS);
  int*   pc    = (int*)(pp + (size_t)NB * NPANEL * KCL * NC);

  k_init<<<NB * KCL, 256, 0, stream>>>(X, centT, cnorm);
  for (int it = 0; it < 10; ++it) {
    k_assign<<<NB * 16, 256, 0, stream>>>(X, centT, cnorm, lab);
    k_psum<<<NB * NPANEL * KCL, 256, 0, stream>>>(X, lab, pp, pc);
    k_combine<<<NB * KCL, 256, 0, stream>>>(pp, pc, centT, cnorm);
  }
  k_assign<<<NB * 16, 256, 0, stream>>>(X, centT, cnorm, lab);
  k_psum<<<NB * NPANEL * KCL, 256, 0, stream>>>(X, lab, pp, pc);
  k_out<<<NB * KCL, 256, 0, stream>>>(pp, pc, out);
}